// Round 5
// baseline (468.711 us; speedup 1.0000x reference)
//
#include <hip/hip_runtime.h>
#include <hip/hip_bf16.h>
#include <stdint.h>

#define B_ 2
#define S_ 2048
#define H_ 2048
#define NH_ 16
#define HD_ 128
#define SCALE_ 0.08838834764831845f
// SCALE * log2(e), folded into Q so flash uses exp2f directly
#define QSCALE_ 0.12751743558230564f

typedef __attribute__((ext_vector_type(8))) short bf16x8;
typedef __attribute__((ext_vector_type(4))) float f32x4;

#define AS1 __attribute__((address_space(1)))
#define AS3 __attribute__((address_space(3)))

__device__ __forceinline__ unsigned short f2bf(float f) {
  union { float f; unsigned int u; } c;
  c.f = f;
  unsigned int u = c.u;
  unsigned int r = (u + 0x7fffu + ((u >> 16) & 1u)) >> 16;
  return (unsigned short)r;
}

__device__ __forceinline__ unsigned int cvt_pk_bf16(float lo, float hi) {
  unsigned int r;
  asm("v_cvt_pk_bf16_f32 %0, %1, %2" : "=v"(r) : "v"(lo), "v"(hi));
  return r;
}

__global__ void cvt_f32_bf16_k(const float* __restrict__ in,
                               unsigned short* __restrict__ out, int n4) {
  int i = blockIdx.x * blockDim.x + threadIdx.x;
  if (i < n4) {
    float4 v = reinterpret_cast<const float4*>(in)[i];
    ushort4 o;
    o.x = f2bf(v.x); o.y = f2bf(v.y); o.z = f2bf(v.z); o.w = f2bf(v.w);
    reinterpret_cast<ushort4*>(out)[i] = o;
  }
}

// ===== 256x256 8-phase GEMM, BK=64, 8 waves (2M x 4N), counted vmcnt =====
// C[M,N] = A[M,K] * Bm[N,K]^T + bias
// LDS: [dbuf][khalf] A regions 256x32 (16KB) at (d*2+kh)*16384,
//      B regions same at 65536 + (d*2+kh)*16384. Total 128KB dynamic.
// Swizzle: colbyte ^= (row&3)<<4 (involution), pre-swizzled global source.
// MODE 0: QKV epilogue scatter (Q pre-scaled, K per-head, V natural, bf16)
// MODE 1: fp32 output + bias
template <int MODE>
__global__ __launch_bounds__(512, 2) void gemm8_k(
    const unsigned short* __restrict__ A,
    const unsigned short* __restrict__ Bm,
    const float* __restrict__ bias,
    int K, int N,
    float* __restrict__ outf,
    unsigned short* __restrict__ Qp,
    unsigned short* __restrict__ Kp,
    unsigned short* __restrict__ Vn) {
  extern __shared__ char smem[];
  const int tid = threadIdx.x;
  const int lane = tid & 63, w = tid >> 6;
  const int wr = w >> 2, wc = w & 3;         // 2M x 4N waves
  const int lr = lane & 15, lg = lane >> 4;
  const int brow = blockIdx.y * 256, bcol = blockIdx.x * 256;
  const int NT = K >> 6;

  f32x4 acc[8][4] = {};

  auto stageA = [&](int u, int kh) {
#pragma unroll
    for (int j = 0; j < 2; ++j) {
      int chunk = j * 512 + tid;
      int row = chunk >> 2;
      int colb = (chunk & 3) << 4;
      int scol = colb ^ ((row & 3) << 4);
      __builtin_amdgcn_global_load_lds(
          (const AS1 unsigned int*)(A + (size_t)(brow + row) * K + u * 64 + kh * 32 + (scol >> 1)),
          (AS3 unsigned int*)(smem + ((u & 1) * 2 + kh) * 16384 + chunk * 16), 16, 0, 0);
    }
  };
  auto stageB = [&](int u, int kh) {
#pragma unroll
    for (int j = 0; j < 2; ++j) {
      int chunk = j * 512 + tid;
      int row = chunk >> 2;
      int colb = (chunk & 3) << 4;
      int scol = colb ^ ((row & 3) << 4);
      __builtin_amdgcn_global_load_lds(
          (const AS1 unsigned int*)(Bm + (size_t)(bcol + row) * K + u * 64 + kh * 32 + (scol >> 1)),
          (AS3 unsigned int*)(smem + 65536 + ((u & 1) * 2 + kh) * 16384 + chunk * 16), 16, 0, 0);
    }
  };
  auto ldA = [&](int d, int kh, int m) -> bf16x8 {
    int row = wr * 128 + m * 16 + lr;
    int byte = (d * 2 + kh) * 16384 + row * 64 + ((lg * 16) ^ ((row & 3) << 4));
    return *reinterpret_cast<const bf16x8*>(smem + byte);
  };
  auto ldB = [&](int d, int kh, int n) -> bf16x8 {
    int row = wc * 64 + n * 16 + lr;
    int byte = 65536 + (d * 2 + kh) * 16384 + row * 64 + ((lg * 16) ^ ((row & 3) << 4));
    return *reinterpret_cast<const bf16x8*>(smem + byte);
  };

  // ---- prologue: stage tile0 (H1-H4) + tile1 (H1-H3); H order A_k0,B_k0,A_k1,B_k1
  stageA(0, 0); stageB(0, 0); stageA(0, 1); stageB(0, 1);
  stageA(1, 0); stageB(1, 0); stageA(1, 1);
  asm volatile("s_waitcnt vmcnt(6)" ::: "memory");
  __builtin_amdgcn_s_barrier();

  for (int T = 0; T < NT; ++T) {
    const int d = T & 1;
    bf16x8 af[8], b0, b1;

    // ===== phase 1: ks=0, n=0,1; stage B_k1(T+1) =====
#pragma unroll
    for (int m = 0; m < 8; ++m) af[m] = ldA(d, 0, m);
    b0 = ldB(d, 0, 0); b1 = ldB(d, 0, 1);
    if (T + 1 < NT) stageB(T + 1, 1);
    __builtin_amdgcn_sched_barrier(0);
    __builtin_amdgcn_s_barrier();
    asm volatile("s_waitcnt lgkmcnt(0)" ::: "memory");
    __builtin_amdgcn_sched_barrier(0);
    __builtin_amdgcn_s_setprio(1);
#pragma unroll
    for (int m = 0; m < 8; ++m) {
      acc[m][0] = __builtin_amdgcn_mfma_f32_16x16x32_bf16(af[m], b0, acc[m][0], 0, 0, 0);
      acc[m][1] = __builtin_amdgcn_mfma_f32_16x16x32_bf16(af[m], b1, acc[m][1], 0, 0, 0);
    }
    __builtin_amdgcn_s_setprio(0);
    __builtin_amdgcn_s_barrier();

    // ===== phase 2: ks=0, n=2,3; stage A_k0(T+2) =====
    b0 = ldB(d, 0, 2); b1 = ldB(d, 0, 3);
    if (T + 2 < NT) stageA(T + 2, 0);
    __builtin_amdgcn_sched_barrier(0);
    __builtin_amdgcn_s_barrier();
    asm volatile("s_waitcnt lgkmcnt(0)" ::: "memory");
    __builtin_amdgcn_sched_barrier(0);
    __builtin_amdgcn_s_setprio(1);
#pragma unroll
    for (int m = 0; m < 8; ++m) {
      acc[m][2] = __builtin_amdgcn_mfma_f32_16x16x32_bf16(af[m], b0, acc[m][2], 0, 0, 0);
      acc[m][3] = __builtin_amdgcn_mfma_f32_16x16x32_bf16(af[m], b1, acc[m][3], 0, 0, 0);
    }
    __builtin_amdgcn_s_setprio(0);
    __builtin_amdgcn_s_barrier();

    // ===== phase 3: ks=1, n=0,1; stage B_k0(T+2) =====
#pragma unroll
    for (int m = 0; m < 8; ++m) af[m] = ldA(d, 1, m);
    b0 = ldB(d, 1, 0); b1 = ldB(d, 1, 1);
    if (T + 2 < NT) stageB(T + 2, 0);
    __builtin_amdgcn_sched_barrier(0);
    __builtin_amdgcn_s_barrier();
    asm volatile("s_waitcnt lgkmcnt(0)" ::: "memory");
    __builtin_amdgcn_sched_barrier(0);
    __builtin_amdgcn_s_setprio(1);
#pragma unroll
    for (int m = 0; m < 8; ++m) {
      acc[m][0] = __builtin_amdgcn_mfma_f32_16x16x32_bf16(af[m], b0, acc[m][0], 0, 0, 0);
      acc[m][1] = __builtin_amdgcn_mfma_f32_16x16x32_bf16(af[m], b1, acc[m][1], 0, 0, 0);
    }
    __builtin_amdgcn_s_setprio(0);
    __builtin_amdgcn_s_barrier();

    // ===== phase 4: ks=1, n=2,3; stage A_k1(T+2); counted vmcnt =====
    b0 = ldB(d, 1, 2); b1 = ldB(d, 1, 3);
    if (T + 2 < NT) stageA(T + 2, 1);
    __builtin_amdgcn_sched_barrier(0);
    __builtin_amdgcn_s_barrier();
    asm volatile("s_waitcnt lgkmcnt(0)" ::: "memory");
    __builtin_amdgcn_sched_barrier(0);
    __builtin_amdgcn_s_setprio(1);
#pragma unroll
    for (int m = 0; m < 8; ++m) {
      acc[m][2] = __builtin_amdgcn_mfma_f32_16x16x32_bf16(af[m], b0, acc[m][2], 0, 0, 0);
      acc[m][3] = __builtin_amdgcn_mfma_f32_16x16x32_bf16(af[m], b1, acc[m][3], 0, 0, 0);
    }
    __builtin_amdgcn_s_setprio(0);
    if (T + 2 < NT)
      asm volatile("s_waitcnt vmcnt(6)" ::: "memory");
    else if (T + 1 < NT)
      asm volatile("s_waitcnt vmcnt(0)" ::: "memory");
    __builtin_amdgcn_s_barrier();
  }

  // ===== epilogue =====
#pragma unroll
  for (int m = 0; m < 8; ++m) {
#pragma unroll
    for (int n = 0; n < 4; ++n) {
      int gcol = bcol + wc * 64 + n * 16 + lr;
      int grow0 = brow + wr * 128 + m * 16 + lg * 4;
      float bv = bias[gcol];
      if (MODE == 1) {
#pragma unroll
        for (int r = 0; r < 4; ++r)
          outf[(size_t)(grow0 + r) * N + gcol] = acc[m][n][r] + bv;
      } else {
        int region = gcol >> 11;
        int o = gcol & 2047;
        int head = o >> 7, dd = o & 127;
#pragma unroll
        for (int r = 0; r < 4; ++r) {
          int grow = grow0 + r;
          int b = grow >> 11, s = grow & 2047;
          float fv = acc[m][n][r] + bv;
          if (region == 0)
            Qp[((size_t)(b * NH_ + head) * S_ + s) * HD_ + dd] = f2bf(fv * QSCALE_);
          else if (region == 1)
            Kp[((size_t)(b * NH_ + head) * S_ + s) * HD_ + dd] = f2bf(fv);
          else
            Vn[(size_t)grow * H_ + o] = f2bf(fv);
        }
      }
    }
  }
}

// Vn[b][s][h*128+d] -> Vt[bh][d][s]
__global__ void transpose_v_k(const unsigned short* __restrict__ Vn,
                              unsigned short* __restrict__ Vt) {
  __shared__ unsigned short t[32][33];
  int bh = blockIdx.z;
  int b = bh >> 4, h = bh & 15;
  int s0 = blockIdx.x * 32, d0 = blockIdx.y * 32;
  int x = threadIdx.x, y0 = threadIdx.y;
#pragma unroll
  for (int yy = 0; yy < 32; yy += 8) {
    int s = s0 + y0 + yy;
    t[y0 + yy][x] = Vn[((size_t)(b * S_ + s)) * H_ + h * HD_ + d0 + x];
  }
  __syncthreads();
#pragma unroll
  for (int yy = 0; yy < 32; yy += 8) {
    int d = d0 + y0 + yy;
    Vt[((size_t)(bh * HD_ + d)) * S_ + s0 + x] = t[x][y0 + yy];
  }
}

// 8 waves/block, q-tile 128 (16 rows/wave), KVBLK=64 staged in LDS (XOR-swizzled).
// Swapped QK^T: sa = mfma(K_frag, Q_frag) so lane holds S[q=lr][k=n*16+lg*4+r]
// -> softmax is lane-local over 16 + 2 shfl_xor; P packed via cvt_pk, b64 LDS writes.
__global__ __launch_bounds__(512, 4) void flash_attn_k(
    const unsigned short* __restrict__ Qp,
    const unsigned short* __restrict__ Kp,
    const unsigned short* __restrict__ Vt,
    unsigned short* __restrict__ ctx) {
  __shared__ unsigned short Kl[64 * 128];   // 16KB, swizzled rows of 256B
  __shared__ unsigned short Vl[128 * 64];   // 16KB, swizzled rows of 128B
  __shared__ unsigned short Pl[8][16 * 72]; // per-wave P tile [q=16][k=64], stride 72

  const int tid = threadIdx.x;
  const int lane = tid & 63, w = tid >> 6;
  const int lr = lane & 15, lg = lane >> 4;
  const int bid = blockIdx.x;
  const int bh = bid & 31;                  // [b*16+h]
  const int qi = 15 - (bid >> 5);           // heavy tiles first
  const int b = bh >> 4, h = bh & 15;
  const int qtile = qi * 128;
  const int qbase = qtile + w * 16;

  const unsigned short* Qh = Qp + (size_t)bh * S_ * HD_;
  const unsigned short* Kh = Kp + (size_t)bh * S_ * HD_;
  const unsigned short* Vh = Vt + (size_t)bh * HD_ * S_;

  bf16x8 qf[4];
#pragma unroll
  for (int dc = 0; dc < 4; ++dc)
    qf[dc] = *reinterpret_cast<const bf16x8*>(Qh + (size_t)(qbase + lr) * HD_ + dc * 32 + lg * 8);

  f32x4 acc_o[8] = {};
  float m_r = -1e30f, l_r = 0.f;            // softmax state for q-row = qbase + lr

  const int nkb = 2 * qi + 2;
  for (int kb = 0; kb < nkb; ++kb) {
    __syncthreads();
    // ---- stage K[64][128] and V[128][64] with pre-swizzled global source ----
    const unsigned short* Kbase = Kh + (size_t)(kb * 64) * HD_;
    const unsigned short* Vbase = Vh + kb * 64;
#pragma unroll
    for (int c2 = 0; c2 < 2; ++c2) {
      int chunk = c2 * 512 + tid;           // 1024 x 16B chunks each
      int krow = chunk >> 4;
      int kcol = (chunk & 15) << 4;
      int kswz = kcol ^ ((krow & 7) << 4);
      __builtin_amdgcn_global_load_lds(
          (const AS1 unsigned int*)(Kbase + krow * HD_ + (kswz >> 1)),
          (AS3 unsigned int*)(Kl + chunk * 8), 16, 0, 0);
      int vrow = chunk >> 3;
      int vcol = (chunk & 7) << 4;
      int vswz = vcol ^ ((vrow & 7) << 4);
      __builtin_amdgcn_global_load_lds(
          (const AS1 unsigned int*)(Vbase + (size_t)vrow * S_ + (vswz >> 1)),
          (AS3 unsigned int*)(Vl + chunk * 8), 16, 0, 0);
    }
    __syncthreads();

    const bool live = (kb * 64 <= qbase + 15);
    if (live) {
      // ---- QK^T (swapped): sa[n][r] = S[q=lr][k = kb*64 + n*16 + lg*4 + r] ----
      f32x4 sa[4] = {};
#pragma unroll
      for (int n = 0; n < 4; ++n) {
        int row = n * 16 + lr;              // k-row in tile
#pragma unroll
        for (int dc = 0; dc < 4; ++dc) {
          int byte = row * 256 + dc * 64 + lg * 16;
          byte ^= (row & 7) << 4;
          bf16x8 kf = *reinterpret_cast<const bf16x8*>(
              reinterpret_cast<const char*>(Kl) + byte);
          sa[n] = __builtin_amdgcn_mfma_f32_16x16x32_bf16(kf, qf[dc], sa[n], 0, 0, 0);
        }
      }

      // ---- mask ----
      if (kb * 64 + 63 > qbase) {
        int rowq = qbase + lr;
#pragma unroll
        for (int n = 0; n < 4; ++n) {
          int col0 = kb * 64 + n * 16 + lg * 4;
#pragma unroll
          for (int r = 0; r < 4; ++r)
            if (col0 + r > rowq) sa[n][r] = -1e30f;
        }
      }

      // ---- online softmax: lane-local over 16 values, cross-lg via shfl_xor ----
      float mx4[4];
#pragma unroll
      for (int n = 0; n < 4; ++n)
        mx4[n] = fmaxf(fmaxf(sa[n][0], sa[n][1]), fmaxf(sa[n][2], sa[n][3]));
      float mx = fmaxf(fmaxf(mx4[0], mx4[1]), fmaxf(mx4[2], mx4[3]));
      mx = fmaxf(mx, __shfl_xor(mx, 16));
      mx = fmaxf(mx, __shfl_xor(mx, 32));
      float mnew = fmaxf(m_r, mx);
      float alpha = exp2f(m_r - mnew);

      float p[4][4];
      float rsn[4];
#pragma unroll
      for (int n = 0; n < 4; ++n) {
#pragma unroll
        for (int r = 0; r < 4; ++r)
          p[n][r] = exp2f(sa[n][r] - mnew);
        rsn[n] = (p[n][0] + p[n][1]) + (p[n][2] + p[n][3]);
      }
      float rs = (rsn[0] + rsn[1]) + (rsn[2] + rsn[3]);
      rs += __shfl_xor(rs, 16);
      rs += __shfl_xor(rs, 32);
      l_r = l_r * alpha + rs;
      m_r = mnew;

      // ---- write P: 4 conflict-free ds_write_b64 ----
#pragma unroll
      for (int n = 0; n < 4; ++n) {
        uint2 pk;
        pk.x = cvt_pk_bf16(p[n][0], p[n][1]);
        pk.y = cvt_pk_bf16(p[n][2], p[n][3]);
        *reinterpret_cast<uint2*>(&Pl[w][lr * 72 + n * 16 + lg * 4]) = pk;
      }

      // ---- rescale O by alpha (broadcast from lanes 0..15) ----
      float al[4];
#pragma unroll
      for (int r = 0; r < 4; ++r)
        al[r] = __shfl(alpha, lg * 4 + r);
#pragma unroll
      for (int nc = 0; nc < 8; ++nc)
#pragma unroll
        for (int r = 0; r < 4; ++r)
          acc_o[nc][r] *= al[r];

      // ---- PV: O[16 x 128] += P[16 x 64] * V[64 x 128] ----
      bf16x8 pa[2];
#pragma unroll
      for (int ks = 0; ks < 2; ++ks)
        pa[ks] = *reinterpret_cast<const bf16x8*>(&Pl[w][lr * 72 + ks * 32 + lg * 8]);
#pragma unroll
      for (int nc = 0; nc < 8; ++nc) {
        int row = nc * 16 + lr;
#pragma unroll
        for (int ks = 0; ks < 2; ++ks) {
          int byte = row * 128 + ks * 64 + lg * 16;
          byte ^= (row & 7) << 4;
          bf16x8 vf = *reinterpret_cast<const bf16x8*>(
              reinterpret_cast<const char*>(Vl) + byte);
          acc_o[nc] = __builtin_amdgcn_mfma_f32_16x16x32_bf16(pa[ks], vf, acc_o[nc], 0, 0, 0);
        }
      }
    }
  }

  float linv = 1.f / l_r;
  float li[4];
#pragma unroll
  for (int r = 0; r < 4; ++r)
    li[r] = __shfl(linv, lg * 4 + r);
#pragma unroll
  for (int nc = 0; nc < 8; ++nc) {
#pragma unroll
    for (int r = 0; r < 4; ++r) {
      int s = qbase + lg * 4 + r;
      ctx[((size_t)(b * S_ + s)) * H_ + h * HD_ + nc * 16 + lr] = f2bf(acc_o[nc][r] * li[r]);
    }
  }
}

extern "C" void kernel_launch(void* const* d_in, const int* in_sizes, int n_in,
                              void* d_out, int out_size, void* d_ws, size_t ws_size,
                              hipStream_t stream) {
  const float* x = (const float*)d_in[0];
  // d_in[1] = attn_mask (causal tril; structure known, ignored)
  const float* w_qkv = (const float*)d_in[2];
  const float* b_qkv = (const float*)d_in[3];
  const float* w_out = (const float*)d_in[4];
  const float* b_out = (const float*)d_in[5];
  float* out = (float*)d_out;

  char* ws = (char*)d_ws;
  unsigned short* xb    = (unsigned short*)(ws);
  unsigned short* wqkvb = (unsigned short*)(ws + 16777216);
  unsigned short* woutb = (unsigned short*)(ws + 41943040);
  unsigned short* Qp    = (unsigned short*)(ws + 50331648);
  unsigned short* Kp    = (unsigned short*)(ws + 67108864);
  unsigned short* Vn    = (unsigned short*)(ws + 83886080);
  unsigned short* Vt    = (unsigned short*)(ws + 100663296);
  unsigned short* ctx   = (unsigned short*)(ws + 117440512);

  // allow 128KB dynamic LDS (idempotent host-side attribute, graph-capture safe)
  hipFuncSetAttribute(reinterpret_cast<const void*>(gemm8_k<0>),
                      hipFuncAttributeMaxDynamicSharedMemorySize, 131072);
  hipFuncSetAttribute(reinterpret_cast<const void*>(gemm8_k<1>),
                      hipFuncAttributeMaxDynamicSharedMemorySize, 131072);

  hipLaunchKernelGGL(cvt_f32_bf16_k, dim3(8192), dim3(256), 0, stream, x, xb, 2097152);
  hipLaunchKernelGGL(cvt_f32_bf16_k, dim3(12288), dim3(256), 0, stream, w_qkv, wqkvb, 3145728);
  hipLaunchKernelGGL(cvt_f32_bf16_k, dim3(4096), dim3(256), 0, stream, w_out, woutb, 1048576);

  hipLaunchKernelGGL((gemm8_k<0>), dim3(24, 16), dim3(512), 131072, stream,
                     xb, wqkvb, b_qkv, 2048, 6144, (float*)nullptr, Qp, Kp, Vn);

  hipLaunchKernelGGL(transpose_v_k, dim3(64, 4, 32), dim3(32, 8), 0, stream, Vn, Vt);

  hipLaunchKernelGGL(flash_attn_k, dim3(512), dim3(512), 0, stream, Qp, Kp, Vt, ctx);

  hipLaunchKernelGGL((gemm8_k<1>), dim3(8, 16), dim3(512), 131072, stream,
                     ctx, woutb, b_out, 2048, 2048, out,
                     (unsigned short*)nullptr, (unsigned short*)nullptr, (unsigned short*)nullptr);
}

// Round 6
// 458.941 us; speedup vs baseline: 1.0213x; 1.0213x over previous
//
#include <hip/hip_runtime.h>
#include <hip/hip_bf16.h>
#include <stdint.h>

#define B_ 2
#define S_ 2048
#define H_ 2048
#define NH_ 16
#define HD_ 128
// SCALE * log2(e), folded into Q so flash uses exp2f directly
#define QSCALE_ 0.12751743558230564f

typedef __attribute__((ext_vector_type(8))) short bf16x8;
typedef __attribute__((ext_vector_type(4))) float f32x4;

#define AS1 __attribute__((address_space(1)))
#define AS3 __attribute__((address_space(3)))

__device__ __forceinline__ unsigned short f2bf(float f) {
  union { float f; unsigned int u; } c;
  c.f = f;
  unsigned int u = c.u;
  unsigned int r = (u + 0x7fffu + ((u >> 16) & 1u)) >> 16;
  return (unsigned short)r;
}

__device__ __forceinline__ unsigned int cvt_pk_bf16(float lo, float hi) {
  unsigned int r;
  asm("v_cvt_pk_bf16_f32 %0, %1, %2" : "=v"(r) : "v"(lo), "v"(hi));
  return r;
}

__global__ void cvt_f32_bf16_k(const float* __restrict__ in,
                               unsigned short* __restrict__ out, int n4) {
  int i = blockIdx.x * blockDim.x + threadIdx.x;
  if (i < n4) {
    float4 v = reinterpret_cast<const float4*>(in)[i];
    ushort4 o;
    o.x = f2bf(v.x); o.y = f2bf(v.y); o.z = f2bf(v.z); o.w = f2bf(v.w);
    reinterpret_cast<ushort4*>(out)[i] = o;
  }
}

// ===== 256x256 GEMM, BK=64, 8 waves (2M x 4N), m201-geometry reconstruction =====
// Regions: [128 rows][64 cols bf16] (128B rows), st_16x32 swizzle
// (byte ^= ((row>>2)&1)<<5), applied pre-swizzled-source + swizzled-read.
// Phases per K-tile (C-quadrants): p1 m0-3/n0-1 (12 reads), p2 m0-3/n2-3 (4),
// p3 m4-7/n0-1 (8), p4 m4-7/n2-3 (0). Stages: p1 Ah0(T+1), p2 Ah1(T+1),
// p3 Bh0(T+2), p4 Bh1(T+2); vmcnt(4) (tail 0) at end of p4 only.
// QKV epilogue scatter (Q pre-scaled, K per-head, V natural, bf16).
__global__ __launch_bounds__(512, 2) void gemm256_k(
    const unsigned short* __restrict__ A,
    const unsigned short* __restrict__ Bm,
    const float* __restrict__ bias,
    int K, int N,
    unsigned short* __restrict__ Qp,
    unsigned short* __restrict__ Kp,
    unsigned short* __restrict__ Vn) {
  extern __shared__ char smem[];
  const int tid = threadIdx.x;
  const int lane = tid & 63, w = tid >> 6;
  const int wr = w >> 2, wc = w & 3;         // 2M x 4N waves
  const int lr = lane & 15, lg = lane >> 4;
  const int brow = blockIdx.y * 256, bcol = blockIdx.x * 256;
  const int NT = K >> 6;

  f32x4 acc[8][4] = {};

  auto stage = [&](const unsigned short* __restrict__ src, int ldsbase,
                   int gr0, int kc0) {
#pragma unroll
    for (int j = 0; j < 2; ++j) {
      int chunk = j * 512 + tid;
      int row = chunk >> 3;                  // 8 x 16B chunks per 128B row
      int colb = (chunk & 7) << 4;
      int scol = colb ^ (((row >> 2) & 1) << 5);   // st_16x32 pre-swizzle
      __builtin_amdgcn_global_load_lds(
          (const AS1 unsigned int*)(src + (size_t)(gr0 + row) * K + kc0 + (scol >> 1)),
          (AS3 unsigned int*)(smem + ldsbase + chunk * 16), 16, 0, 0);
    }
  };
  auto aoff = [&](int d, int h) { return (d * 2 + h) * 16384; };
  auto boff = [&](int d, int h) { return 65536 + (d * 2 + h) * 16384; };

  auto ldA = [&](int d, int m, int kk) -> bf16x8 {
    int rowr = m * 16 + lr;
    int off = (kk * 64 + lg * 16) ^ (((rowr >> 2) & 1) << 5);
    return *reinterpret_cast<const bf16x8*>(smem + aoff(d, wr) + rowr * 128 + off);
  };
  auto ldB = [&](int d, int n, int kk) -> bf16x8 {
    int row = wc * 64 + n * 16 + lr;
    int h = row >> 7, rowr = row & 127;
    int off = (kk * 64 + lg * 16) ^ (((rowr >> 2) & 1) << 5);
    return *reinterpret_cast<const bf16x8*>(smem + boff(d, h) + rowr * 128 + off);
  };

  // ---- prologue: tile0 all 4 units + tile1 B units; drain to tile0-complete
  stage(A,  aoff(0, 0), brow +   0, 0);   // Ah0(0)
  stage(A,  aoff(0, 1), brow + 128, 0);   // Ah1(0)
  stage(Bm, boff(0, 0), bcol +   0, 0);   // Bh0(0)
  stage(Bm, boff(0, 1), bcol + 128, 0);   // Bh1(0)
  stage(Bm, boff(1, 0), bcol +   0, 64);  // Bh0(1)
  stage(Bm, boff(1, 1), bcol + 128, 64);  // Bh1(1)
  asm volatile("s_waitcnt vmcnt(4)" ::: "memory");
  __builtin_amdgcn_s_barrier();

  for (int T = 0; T < NT; ++T) {
    const int d = T & 1;
    bf16x8 af[4][2], bA[2][2], bB[2][2];

    // ===== phase 1: m0-3 x n0-1 (12 reads); stage Ah0(T+1) =====
#pragma unroll
    for (int m = 0; m < 4; ++m) { af[m][0] = ldA(d, m, 0); af[m][1] = ldA(d, m, 1); }
    bA[0][0] = ldB(d, 0, 0); bA[0][1] = ldB(d, 0, 1);
    bA[1][0] = ldB(d, 1, 0); bA[1][1] = ldB(d, 1, 1);
    if (T + 1 < NT) stage(A, aoff(d ^ 1, 0), brow + 0, (T + 1) * 64);
    __builtin_amdgcn_s_barrier();
    asm volatile("s_waitcnt lgkmcnt(0)" ::: "memory");
    __builtin_amdgcn_sched_barrier(0);
    __builtin_amdgcn_s_setprio(1);
#pragma unroll
    for (int m = 0; m < 4; ++m)
#pragma unroll
      for (int n = 0; n < 2; ++n) {
        acc[m][n] = __builtin_amdgcn_mfma_f32_16x16x32_bf16(af[m][0], bA[n][0], acc[m][n], 0, 0, 0);
        acc[m][n] = __builtin_amdgcn_mfma_f32_16x16x32_bf16(af[m][1], bA[n][1], acc[m][n], 0, 0, 0);
      }
    __builtin_amdgcn_s_setprio(0);
    __builtin_amdgcn_s_barrier();

    // ===== phase 2: m0-3 x n2-3 (4 reads); stage Ah1(T+1) =====
    bB[0][0] = ldB(d, 2, 0); bB[0][1] = ldB(d, 2, 1);
    bB[1][0] = ldB(d, 3, 0); bB[1][1] = ldB(d, 3, 1);
    if (T + 1 < NT) stage(A, aoff(d ^ 1, 1), brow + 128, (T + 1) * 64);
    __builtin_amdgcn_s_barrier();
    asm volatile("s_waitcnt lgkmcnt(0)" ::: "memory");
    __builtin_amdgcn_sched_barrier(0);
    __builtin_amdgcn_s_setprio(1);
#pragma unroll
    for (int m = 0; m < 4; ++m)
#pragma unroll
      for (int n = 0; n < 2; ++n) {
        acc[m][n + 2] = __builtin_amdgcn_mfma_f32_16x16x32_bf16(af[m][0], bB[n][0], acc[m][n + 2], 0, 0, 0);
        acc[m][n + 2] = __builtin_amdgcn_mfma_f32_16x16x32_bf16(af[m][1], bB[n][1], acc[m][n + 2], 0, 0, 0);
      }
    __builtin_amdgcn_s_setprio(0);
    __builtin_amdgcn_s_barrier();

    // ===== phase 3: m4-7 x n0-1 (8 reads); stage Bh0(T+2) =====
#pragma unroll
    for (int m = 0; m < 4; ++m) { af[m][0] = ldA(d, m + 4, 0); af[m][1] = ldA(d, m + 4, 1); }
    if (T + 2 < NT) stage(Bm, boff(d, 0), bcol + 0, (T + 2) * 64);
    __builtin_amdgcn_s_barrier();
    asm volatile("s_waitcnt lgkmcnt(0)" ::: "memory");
    __builtin_amdgcn_sched_barrier(0);
    __builtin_amdgcn_s_setprio(1);
#pragma unroll
    for (int m = 0; m < 4; ++m)
#pragma unroll
      for (int n = 0; n < 2; ++n) {
        acc[m + 4][n] = __builtin_amdgcn_mfma_f32_16x16x32_bf16(af[m][0], bA[n][0], acc[m + 4][n], 0, 0, 0);
        acc[m + 4][n] = __builtin_amdgcn_mfma_f32_16x16x32_bf16(af[m][1], bA[n][1], acc[m + 4][n], 0, 0, 0);
      }
    __builtin_amdgcn_s_setprio(0);
    __builtin_amdgcn_s_barrier();

    // ===== phase 4: m4-7 x n2-3 (0 reads); stage Bh1(T+2); counted vmcnt =====
    if (T + 2 < NT) stage(Bm, boff(d, 1), bcol + 128, (T + 2) * 64);
    __builtin_amdgcn_s_setprio(1);
#pragma unroll
    for (int m = 0; m < 4; ++m)
#pragma unroll
      for (int n = 0; n < 2; ++n) {
        acc[m + 4][n + 2] = __builtin_amdgcn_mfma_f32_16x16x32_bf16(af[m][0], bB[n][0], acc[m + 4][n + 2], 0, 0, 0);
        acc[m + 4][n + 2] = __builtin_amdgcn_mfma_f32_16x16x32_bf16(af[m][1], bB[n][1], acc[m + 4][n + 2], 0, 0, 0);
      }
    __builtin_amdgcn_s_setprio(0);
    if (T + 1 < NT) {
      if (T + 2 < NT)
        asm volatile("s_waitcnt vmcnt(4)" ::: "memory");
      else
        asm volatile("s_waitcnt vmcnt(0)" ::: "memory");
    }
    __builtin_amdgcn_s_barrier();
  }

  // ===== epilogue: QKV scatter =====
#pragma unroll
  for (int m = 0; m < 8; ++m) {
#pragma unroll
    for (int n = 0; n < 4; ++n) {
      int gcol = bcol + wc * 64 + n * 16 + lr;
      int grow0 = brow + wr * 128 + m * 16 + lg * 4;
      float bv = bias[gcol];
      int region = gcol >> 11;
      int o = gcol & 2047;
      int head = o >> 7, dd = o & 127;
#pragma unroll
      for (int r = 0; r < 4; ++r) {
        int grow = grow0 + r;
        int b = grow >> 11, s = grow & 2047;
        float fv = acc[m][n][r] + bv;
        if (region == 0)
          Qp[((size_t)(b * NH_ + head) * S_ + s) * HD_ + dd] = f2bf(fv * QSCALE_);
        else if (region == 1)
          Kp[((size_t)(b * NH_ + head) * S_ + s) * HD_ + dd] = f2bf(fv);
        else
          Vn[(size_t)grow * H_ + o] = f2bf(fv);
      }
    }
  }
}

// ===== 128x128 2-phase GEMM (proven m97 structure), fp32 out + bias =====
__global__ __launch_bounds__(256) void gemm128_k(
    const unsigned short* __restrict__ A,
    const unsigned short* __restrict__ Bm,
    const float* __restrict__ bias,
    int K, int N,
    float* __restrict__ outf) {
  __shared__ unsigned short Al[128 * 32];
  __shared__ unsigned short Bl[128 * 32];
  const int tid = threadIdx.x;
  const int lane = tid & 63;
  const int w = tid >> 6;
  const int wr = w >> 1, wc = w & 1;
  const int brow = blockIdx.y * 128, bcol = blockIdx.x * 128;
  const int lr = lane & 15, lg = lane >> 4;
  f32x4 acc[4][4] = {};

  for (int kb = 0; kb < K; kb += 32) {
    __syncthreads();
#pragma unroll
    for (int p = 0; p < 2; ++p) {
      int c = p * 256 + tid;
      int row = c >> 2, kc = (c & 3) * 8;
      __builtin_amdgcn_global_load_lds(
          (const AS1 unsigned int*)(A + (size_t)(brow + row) * K + kb + kc),
          (AS3 unsigned int*)(Al + c * 8), 16, 0, 0);
      __builtin_amdgcn_global_load_lds(
          (const AS1 unsigned int*)(Bm + (size_t)(bcol + row) * K + kb + kc),
          (AS3 unsigned int*)(Bl + c * 8), 16, 0, 0);
    }
    __syncthreads();
    bf16x8 af[4], bfr[4];
#pragma unroll
    for (int m = 0; m < 4; ++m)
      af[m] = *reinterpret_cast<const bf16x8*>(&Al[(wr * 64 + m * 16 + lr) * 32 + lg * 8]);
#pragma unroll
    for (int n = 0; n < 4; ++n)
      bfr[n] = *reinterpret_cast<const bf16x8*>(&Bl[(wc * 64 + n * 16 + lr) * 32 + lg * 8]);
#pragma unroll
    for (int m = 0; m < 4; ++m)
#pragma unroll
      for (int n = 0; n < 4; ++n)
        acc[m][n] = __builtin_amdgcn_mfma_f32_16x16x32_bf16(af[m], bfr[n], acc[m][n], 0, 0, 0);
  }

#pragma unroll
  for (int m = 0; m < 4; ++m) {
#pragma unroll
    for (int n = 0; n < 4; ++n) {
      int gcol = bcol + wc * 64 + n * 16 + lr;
      int grow0 = brow + wr * 64 + m * 16 + lg * 4;
      float bv = bias[gcol];
#pragma unroll
      for (int r = 0; r < 4; ++r)
        outf[(size_t)(grow0 + r) * N + gcol] = acc[m][n][r] + bv;
    }
  }
}

// Vn[b][s][h*128+d] -> Vt[bh][d][s]
__global__ void transpose_v_k(const unsigned short* __restrict__ Vn,
                              unsigned short* __restrict__ Vt) {
  __shared__ unsigned short t[32][33];
  int bh = blockIdx.z;
  int b = bh >> 4, h = bh & 15;
  int s0 = blockIdx.x * 32, d0 = blockIdx.y * 32;
  int x = threadIdx.x, y0 = threadIdx.y;
#pragma unroll
  for (int yy = 0; yy < 32; yy += 8) {
    int s = s0 + y0 + yy;
    t[y0 + yy][x] = Vn[((size_t)(b * S_ + s)) * H_ + h * HD_ + d0 + x];
  }
  __syncthreads();
#pragma unroll
  for (int yy = 0; yy < 32; yy += 8) {
    int d = d0 + y0 + yy;
    Vt[((size_t)(bh * HD_ + d)) * S_ + s0 + x] = t[x][y0 + yy];
  }
}

// 8 waves/block, q-tile 128 (16 rows/wave), KVBLK=64 staged in LDS (XOR-swizzled).
// Swapped QK^T: sa = mfma(K_frag, Q_frag) so lane holds S[q=lr][k=n*16+lg*4+r]
// -> softmax is lane-local over 16 + 2 shfl_xor; P packed via cvt_pk, b64 LDS writes.
__global__ __launch_bounds__(512, 4) void flash_attn_k(
    const unsigned short* __restrict__ Qp,
    const unsigned short* __restrict__ Kp,
    const unsigned short* __restrict__ Vt,
    unsigned short* __restrict__ ctx) {
  __shared__ unsigned short Kl[64 * 128];
  __shared__ unsigned short Vl[128 * 64];
  __shared__ unsigned short Pl[8][16 * 72];

  const int tid = threadIdx.x;
  const int lane = tid & 63, w = tid >> 6;
  const int lr = lane & 15, lg = lane >> 4;
  const int bid = blockIdx.x;
  const int bh = bid & 31;
  const int qi = 15 - (bid >> 5);
  const int b = bh >> 4, h = bh & 15;
  const int qtile = qi * 128;
  const int qbase = qtile + w * 16;

  const unsigned short* Qh = Qp + (size_t)bh * S_ * HD_;
  const unsigned short* Kh = Kp + (size_t)bh * S_ * HD_;
  const unsigned short* Vh = Vt + (size_t)bh * HD_ * S_;

  bf16x8 qf[4];
#pragma unroll
  for (int dc = 0; dc < 4; ++dc)
    qf[dc] = *reinterpret_cast<const bf16x8*>(Qh + (size_t)(qbase + lr) * HD_ + dc * 32 + lg * 8);

  f32x4 acc_o[8] = {};
  float m_r = -1e30f, l_r = 0.f;

  const int nkb = 2 * qi + 2;
  for (int kb = 0; kb < nkb; ++kb) {
    __syncthreads();
    const unsigned short* Kbase = Kh + (size_t)(kb * 64) * HD_;
    const unsigned short* Vbase = Vh + kb * 64;
#pragma unroll
    for (int c2 = 0; c2 < 2; ++c2) {
      int chunk = c2 * 512 + tid;
      int krow = chunk >> 4;
      int kcol = (chunk & 15) << 4;
      int kswz = kcol ^ ((krow & 7) << 4);
      __builtin_amdgcn_global_load_lds(
          (const AS1 unsigned int*)(Kbase + krow * HD_ + (kswz >> 1)),
          (AS3 unsigned int*)(Kl + chunk * 8), 16, 0, 0);
      int vrow = chunk >> 3;
      int vcol = (chunk & 7) << 4;
      int vswz = vcol ^ ((vrow & 7) << 4);
      __builtin_amdgcn_global_load_lds(
          (const AS1 unsigned int*)(Vbase + (size_t)vrow * S_ + (vswz >> 1)),
          (AS3 unsigned int*)(Vl + chunk * 8), 16, 0, 0);
    }
    __syncthreads();

    const bool live = (kb * 64 <= qbase + 15);
    if (live) {
      f32x4 sa[4] = {};
#pragma unroll
      for (int n = 0; n < 4; ++n) {
        int row = n * 16 + lr;
#pragma unroll
        for (int dc = 0; dc < 4; ++dc) {
          int byte = row * 256 + dc * 64 + lg * 16;
          byte ^= (row & 7) << 4;
          bf16x8 kf = *reinterpret_cast<const bf16x8*>(
              reinterpret_cast<const char*>(Kl) + byte);
          sa[n] = __builtin_amdgcn_mfma_f32_16x16x32_bf16(kf, qf[dc], sa[n], 0, 0, 0);
        }
      }

      if (kb * 64 + 63 > qbase) {
        int rowq = qbase + lr;
#pragma unroll
        for (int n = 0; n < 4; ++n) {
          int col0 = kb * 64 + n * 16 + lg * 4;
#pragma unroll
          for (int r = 0; r < 4; ++r)
            if (col0 + r > rowq) sa[n][r] = -1e30f;
        }
      }

      float mx4[4];
#pragma unroll
      for (int n = 0; n < 4; ++n)
        mx4[n] = fmaxf(fmaxf(sa[n][0], sa[n][1]), fmaxf(sa[n][2], sa[n][3]));
      float mx = fmaxf(fmaxf(mx4[0], mx4[1]), fmaxf(mx4[2], mx4[3]));
      mx = fmaxf(mx, __shfl_xor(mx, 16));
      mx = fmaxf(mx, __shfl_xor(mx, 32));
      float mnew = fmaxf(m_r, mx);
      float alpha = exp2f(m_r - mnew);

      float p[4][4];
      float rsn[4];
#pragma unroll
      for (int n = 0; n < 4; ++n) {
#pragma unroll
        for (int r = 0; r < 4; ++r)
          p[n][r] = exp2f(sa[n][r] - mnew);
        rsn[n] = (p[n][0] + p[n][1]) + (p[n][2] + p[n][3]);
      }
      float rs = (rsn[0] + rsn[1]) + (rsn[2] + rsn[3]);
      rs += __shfl_xor(rs, 16);
      rs += __shfl_xor(rs, 32);
      l_r = l_r * alpha + rs;
      m_r = mnew;

#pragma unroll
      for (int n = 0; n < 4; ++n) {
        uint2 pk;
        pk.x = cvt_pk_bf16(p[n][0], p[n][1]);
        pk.y = cvt_pk_bf16(p[n][2], p[n][3]);
        *reinterpret_cast<uint2*>(&Pl[w][lr * 72 + n * 16 + lg * 4]) = pk;
      }

      float al[4];
#pragma unroll
      for (int r = 0; r < 4; ++r)
        al[r] = __shfl(alpha, lg * 4 + r);
#pragma unroll
      for (int nc = 0; nc < 8; ++nc)
#pragma unroll
        for (int r = 0; r < 4; ++r)
          acc_o[nc][r] *= al[r];

      bf16x8 pa[2];
#pragma unroll
      for (int ks = 0; ks < 2; ++ks)
        pa[ks] = *reinterpret_cast<const bf16x8*>(&Pl[w][lr * 72 + ks * 32 + lg * 8]);
#pragma unroll
      for (int nc = 0; nc < 8; ++nc) {
        int row = nc * 16 + lr;
#pragma unroll
        for (int ks = 0; ks < 2; ++ks) {
          int byte = row * 128 + ks * 64 + lg * 16;
          byte ^= (row & 7) << 4;
          bf16x8 vf = *reinterpret_cast<const bf16x8*>(
              reinterpret_cast<const char*>(Vl) + byte);
          acc_o[nc] = __builtin_amdgcn_mfma_f32_16x16x32_bf16(pa[ks], vf, acc_o[nc], 0, 0, 0);
        }
      }
    }
  }

  float linv = 1.f / l_r;
  float li[4];
#pragma unroll
  for (int r = 0; r < 4; ++r)
    li[r] = __shfl(linv, lg * 4 + r);
#pragma unroll
  for (int nc = 0; nc < 8; ++nc) {
#pragma unroll
    for (int r = 0; r < 4; ++r) {
      int s = qbase + lg * 4 + r;
      ctx[((size_t)(b * S_ + s)) * H_ + h * HD_ + nc * 16 + lr] = f2bf(acc_o[nc][r] * li[r]);
    }
  }
}

extern "C" void kernel_launch(void* const* d_in, const int* in_sizes, int n_in,
                              void* d_out, int out_size, void* d_ws, size_t ws_size,
                              hipStream_t stream) {
  const float* x = (const float*)d_in[0];
  // d_in[1] = attn_mask (causal tril; structure known, ignored)
  const float* w_qkv = (const float*)d_in[2];
  const float* b_qkv = (const float*)d_in[3];
  const float* w_out = (const float*)d_in[4];
  const float* b_out = (const float*)d_in[5];
  float* out = (float*)d_out;

  char* ws = (char*)d_ws;
  unsigned short* xb    = (unsigned short*)(ws);
  unsigned short* wqkvb = (unsigned short*)(ws + 16777216);
  unsigned short* woutb = (unsigned short*)(ws + 41943040);
  unsigned short* Qp    = (unsigned short*)(ws + 50331648);
  unsigned short* Kp    = (unsigned short*)(ws + 67108864);
  unsigned short* Vn    = (unsigned short*)(ws + 83886080);
  unsigned short* Vt    = (unsigned short*)(ws + 100663296);
  unsigned short* ctx   = (unsigned short*)(ws + 117440512);

  hipFuncSetAttribute(reinterpret_cast<const void*>(gemm256_k),
                      hipFuncAttributeMaxDynamicSharedMemorySize, 131072);

  hipLaunchKernelGGL(cvt_f32_bf16_k, dim3(8192), dim3(256), 0, stream, x, xb, 2097152);
  hipLaunchKernelGGL(cvt_f32_bf16_k, dim3(12288), dim3(256), 0, stream, w_qkv, wqkvb, 3145728);
  hipLaunchKernelGGL(cvt_f32_bf16_k, dim3(4096), dim3(256), 0, stream, w_out, woutb, 1048576);

  hipLaunchKernelGGL(gemm256_k, dim3(24, 16), dim3(512), 131072, stream,
                     xb, wqkvb, b_qkv, 2048, 6144, Qp, Kp, Vn);

  hipLaunchKernelGGL(transpose_v_k, dim3(64, 4, 32), dim3(32, 8), 0, stream, Vn, Vt);

  hipLaunchKernelGGL(flash_attn_k, dim3(512), dim3(512), 0, stream, Qp, Kp, Vt, ctx);

  hipLaunchKernelGGL(gemm128_k, dim3(16, 32), dim3(256), 0, stream,
                     ctx, woutb, b_out, 2048, 2048, out);
}